// Round 1
// baseline (129.106 us; speedup 1.0000x reference)
//
#include <hip/hip_runtime.h>

#define WAVE 64
#define WPB 4                // waves (rays) per block
#define BLOCK (WAVE * WPB)
#define SC 256               // coarse samples per ray
#define SF 128               // fine (importance) samples per ray

__device__ __forceinline__ float fexp2(float x) {
#if __has_builtin(__builtin_amdgcn_exp2f)
    return __builtin_amdgcn_exp2f(x);
#else
    return exp2f(x);
#endif
}
__device__ __forceinline__ float frcp(float x) {
#if __has_builtin(__builtin_amdgcn_rcpf)
    return __builtin_amdgcn_rcpf(x);
#else
    return 1.0f / x;
#endif
}
__device__ __forceinline__ float frsq(float x) {
#if __has_builtin(__builtin_amdgcn_rsqf)
    return __builtin_amdgcn_rsqf(x);
#else
    return rsqrtf(x);
#endif
}

__global__ __launch_bounds__(BLOCK) void nerf_render(
    const float* __restrict__ rays_o, const float* __restrict__ rays_d,
    const float* __restrict__ bgp, float* __restrict__ out, int N) {
    const int wid  = threadIdx.x >> 6;
    const int lane = threadIdx.x & 63;
    const int ray  = blockIdx.x * WPB + wid;
    __shared__ float cdf_s[WPB][SC];
    if (ray >= N) return;

    const float L2_10 = 3.3219280948873623f;   // log2(10)
    const float L2_E  = 1.4426950408889634f;   // log2(e)
    const float DLT   = 0.0078125f;            // 1/128

    float ox = rays_o[ray * 3 + 0], oy = rays_o[ray * 3 + 1], oz = rays_o[ray * 3 + 2];
    float dx = rays_d[ray * 3 + 0], dy = rays_d[ray * 3 + 1], dz = rays_d[ray * 3 + 2];
    {   // normalize direction
        float rn = frsq(dx * dx + dy * dy + dz * dz);
        dx *= rn; dy *= rn; dz *= rn;
    }

    // ---------------- coarse pass: lane owns k = 4*lane .. 4*lane+3 ----------------
    float e[4], w[4];
    float lp = 1.0f;  // lane product of e_k = exp(-sig*delta)
#pragma unroll
    for (int i = 0; i < 4; i++) {
        int k = (lane << 2) + i;
        float zl = -1.0f + (float)k * DLT;           // exact
        float z  = fexp2(zl * L2_10);                // 10^zl
        float px = fmaf(dx, z, ox), py = fmaf(dy, z, oy), pz = fmaf(dz, z, oz);
        float nsq = px * px + py * py + pz * pz;
        float ssq;
        if (nsq > 1.0f) { float rn = frsq(nsq); float t2 = 2.0f - rn; ssq = t2 * t2; }
        else            { ssq = nsq; }
        float sig = 25.0f * fexp2(-4.0f * L2_E * ssq);
        float q = (k == SC - 1) ? 0.0f : sig * DLT;  // last delta = 0
        e[i] = fexp2(-L2_E * q);
        lp *= e[i];
    }
    // exclusive product scan across lanes -> incoming transmittance
    float ip = lp;
    for (int off = 1; off < 64; off <<= 1) {
        float t = __shfl_up(ip, off, 64);
        if (lane >= off) ip *= t;
    }
    float tin = __shfl_up(ip, 1, 64);
    if (lane == 0) tin = 1.0f;
    {
        float t = tin;
#pragma unroll
        for (int i = 0; i < 4; i++) { w[i] = (1.0f - e[i]) * t; t *= e[i]; }
    }
    // reweight: 0.5*(max(w[k-1],w[k]) + max(w[k],w[k+1])) + 1e-4/256  (scale 0.5 cancels)
    float wprev = __shfl_up(w[3], 1, 64);  if (lane == 0)  wprev = 0.0f;
    float wnext = __shfl_down(w[0], 1, 64); if (lane == 63) wnext = 0.0f;
    const float CADD = 1e-4f / 256.0f;
    float wr0 = 0.5f * (fmaxf(wprev, w[0]) + fmaxf(w[0], w[1])) + CADD;
    float wr1 = 0.5f * (fmaxf(w[0], w[1]) + fmaxf(w[1], w[2])) + CADD;
    float wr2 = 0.5f * (fmaxf(w[1], w[2]) + fmaxf(w[2], w[3])) + CADD;
    float wr3 = 0.5f * (fmaxf(w[2], w[3]) + fmaxf(w[3], wnext)) + CADD;
    // CDF: local inclusive sums + wave add-scan
    float s0 = wr0, s1 = s0 + wr1, s2 = s1 + wr2, s3 = s2 + wr3;
    float base = s3;
    for (int off = 1; off < 64; off <<= 1) {
        float t = __shfl_up(base, off, 64);
        if (lane >= off) base += t;
    }
    float tot = __shfl(base, 63, 64);
    float exb = __shfl_up(base, 1, 64);
    if (lane == 0) exb = 0.0f;
    float invT = 1.0f / tot;
    cdf_s[wid][(lane << 2) + 0] = (exb + s0) * invT;
    cdf_s[wid][(lane << 2) + 1] = (exb + s1) * invT;
    cdf_s[wid][(lane << 2) + 2] = (exb + s2) * invT;
    cdf_s[wid][(lane << 2) + 3] = (exb + s3) * invT;
    __syncthreads();
    const float* cdf = cdf_s[wid];

    // ---------------- inverse-CDF sampling: lane owns j = 2*lane, 2*lane+1 ----------------
    float zlf[2];
#pragma unroll
    for (int jj = 0; jj < 2; jj++) {
        int j = (lane << 1) + jj;
        float u = ((float)j + 0.5f) * (1.0f / 128.0f);
        int lo = 0, hi = SC;
        while (lo < hi) {   // first k with cdf[k] > u  (searchsorted side='right')
            int mid = (lo + hi) >> 1;
            if (cdf[mid] <= u) lo = mid + 1; else hi = mid;
        }
        int inds  = lo;
        int below = inds - 1; if (below < 0) below = 0;
        int above = inds;     if (above > SC - 1) above = SC - 1;
        float c0 = cdf[below], c1 = cdf[above];
        float b0 = -1.0f + (float)below * DLT;
        float b1 = -1.0f + (float)above * DLT;
        float dnm = c1 - c0;
        dnm = (dnm < 1e-8f) ? 1.0f : dnm;
        float t = (u - c0) / dnm;
        t = t < 0.0f ? 0.0f : (t > 1.0f ? 1.0f : t);
        zlf[jj] = fmaf(t, b1 - b0, b0);
    }

    // ---------------- fine render ----------------
    float zlf2 = __shfl_down(zlf[0], 1, 64);       // zlf[2*lane+2]
    float del[2];
    del[0] = zlf[1] - zlf[0];
    del[1] = (lane == 63) ? 0.0f : (zlf2 - zlf[1]);
    float ef[2], rgbv[2][3], invz[2];
    float lpf = 1.0f;
#pragma unroll
    for (int jj = 0; jj < 2; jj++) {
        float zf = fexp2(zlf[jj] * L2_10);
        invz[jj] = frcp(zf);
        float px = fmaf(dx, zf, ox), py = fmaf(dy, zf, oy), pz = fmaf(dz, zf, oz);
        float nsq = px * px + py * py + pz * pz;
        float ssq, fac;
        if (nsq > 1.0f) { float rn = frsq(nsq); float t2 = 2.0f - rn; ssq = t2 * t2; fac = rn * t2; }
        else            { ssq = nsq; fac = 1.0f; }
        float sig = 25.0f * fexp2(-4.0f * L2_E * ssq);
        ef[jj] = fexp2(-L2_E * sig * del[jj]);
        float sx = px * fac, sy = py * fac, sz = pz * fac;
        rgbv[jj][0] = frcp(1.0f + fexp2(-L2_E * fmaf(0.1f, dx, sx)));
        rgbv[jj][1] = frcp(1.0f + fexp2(-L2_E * fmaf(0.1f, dy, sy)));
        rgbv[jj][2] = frcp(1.0f + fexp2(-L2_E * fmaf(0.1f, dz, sz)));
        lpf *= ef[jj];
    }
    float ipf = lpf;
    for (int off = 1; off < 64; off <<= 1) {
        float t = __shfl_up(ipf, off, 64);
        if (lane >= off) ipf *= t;
    }
    float tinf = __shfl_up(ipf, 1, 64);
    if (lane == 0) tinf = 1.0f;
    float wf0 = (1.0f - ef[0]) * tinf;
    float wf1 = (1.0f - ef[1]) * (tinf * ef[0]);

    float ar = wf0 * rgbv[0][0] + wf1 * rgbv[1][0];
    float ag = wf0 * rgbv[0][1] + wf1 * rgbv[1][1];
    float ab = wf0 * rgbv[0][2] + wf1 * rgbv[1][2];
    float aw = wf0 + wf1;
    float ai = wf0 * invz[0] + wf1 * invz[1];
    for (int off = 32; off; off >>= 1) {
        ar += __shfl_xor(ar, off, 64);
        ag += __shfl_xor(ag, off, 64);
        ab += __shfl_xor(ab, off, 64);
        aw += __shfl_xor(aw, off, 64);
        ai += __shfl_xor(ai, off, 64);
    }

    // ---------------- outputs: [image N*3][wf N*128][zvs N*128][invdepth N] ----------------
    const size_t NN = (size_t)N;
    float* wf_base  = out + 3 * NN;
    float* zvs_base = out + 3 * NN + NN * (size_t)SF;
    float* inv_base = out + 3 * NN + 2 * NN * (size_t)SF;
    size_t col = (size_t)ray * SF + (size_t)(lane << 1);
    *(float2*)(wf_base + col)  = make_float2(wf0, wf1);
    *(float2*)(zvs_base + col) = make_float2((zlf[0] + 1.0f) * 0.5f, (zlf[1] + 1.0f) * 0.5f);
    if (lane == 0) {
        float om = 1.0f - aw;
        out[ray * 3 + 0] = fmaf(om, bgp[0], ar);
        out[ray * 3 + 1] = fmaf(om, bgp[1], ag);
        out[ray * 3 + 2] = fmaf(om, bgp[2], ab);
        inv_base[ray] = ai;
    }
}

extern "C" void kernel_launch(void* const* d_in, const int* in_sizes, int n_in,
                              void* d_out, int out_size, void* d_ws, size_t ws_size,
                              hipStream_t stream) {
    const float* rays_o = (const float*)d_in[0];
    const float* rays_d = (const float*)d_in[1];
    const float* bg     = (const float*)d_in[2];
    float* out = (float*)d_out;
    int N = in_sizes[0] / 3;
    int blocks = (N + WPB - 1) / WPB;
    nerf_render<<<blocks, BLOCK, 0, stream>>>(rays_o, rays_d, bg, out, N);
}

// Round 3
// 122.849 us; speedup vs baseline: 1.0509x; 1.0509x over previous
//
#include <hip/hip_runtime.h>

#define WPB 4                // waves (rays) per block
#define BLOCK (64 * WPB)
#define SC 256               // coarse samples per ray
#define SF 128               // fine (importance) samples per ray

typedef float v2f __attribute__((ext_vector_type(2)));

__device__ __forceinline__ float fexp2(float x) {
#if __has_builtin(__builtin_amdgcn_exp2f)
    return __builtin_amdgcn_exp2f(x);
#else
    return exp2f(x);
#endif
}
__device__ __forceinline__ float frcp(float x) {
#if __has_builtin(__builtin_amdgcn_rcpf)
    return __builtin_amdgcn_rcpf(x);
#else
    return 1.0f / x;
#endif
}
__device__ __forceinline__ float frsq(float x) {
#if __has_builtin(__builtin_amdgcn_rsqf)
    return __builtin_amdgcn_rsqf(x);
#else
    return rsqrtf(x);
#endif
}

// DPP move with identity fill: invalid-source lanes AND row_mask-disabled
// lanes read `oldv` (bound_ctrl=false). rmask selects which 16-lane rows
// are written — REQUIRED for the bcast steps of a wave64 scan.
#define DPPF(oldv, x, ctrl, rmask)                                              \
    __int_as_float(__builtin_amdgcn_update_dpp(                                 \
        __float_as_int(oldv), __float_as_int(x), (ctrl), (rmask), 0xf, false))

// gfx9 DPP ctrl codes
#define ROW_SHR1   0x111
#define ROW_SHR2   0x112
#define ROW_SHR4   0x114
#define ROW_SHR8   0x118
#define WAVE_SHR1  0x138
#define ROW_BC15   0x142
#define ROW_BC31   0x143

__device__ __forceinline__ float scan_mul_incl(float x) {
    x *= DPPF(1.0f, x, ROW_SHR1, 0xf);
    x *= DPPF(1.0f, x, ROW_SHR2, 0xf);
    x *= DPPF(1.0f, x, ROW_SHR4, 0xf);
    x *= DPPF(1.0f, x, ROW_SHR8, 0xf);
    x *= DPPF(1.0f, x, ROW_BC15, 0xa);   // rows 1,3 only
    x *= DPPF(1.0f, x, ROW_BC31, 0xc);   // rows 2,3 only
    return x;                      // inclusive product; lane63 = total
}
__device__ __forceinline__ float scan_add_incl(float x) {
    x += DPPF(0.0f, x, ROW_SHR1, 0xf);
    x += DPPF(0.0f, x, ROW_SHR2, 0xf);
    x += DPPF(0.0f, x, ROW_SHR4, 0xf);
    x += DPPF(0.0f, x, ROW_SHR8, 0xf);
    x += DPPF(0.0f, x, ROW_BC15, 0xa);   // rows 1,3 only
    x += DPPF(0.0f, x, ROW_BC31, 0xc);   // rows 2,3 only
    return x;                      // inclusive sum; lane63 = total
}
__device__ __forceinline__ float readlane63(float x) {
    return __int_as_float(__builtin_amdgcn_readlane(__float_as_int(x), 63));
}

__global__ __launch_bounds__(BLOCK) void nerf_render(
    const float* __restrict__ rays_o, const float* __restrict__ rays_d,
    const float* __restrict__ bgp, float* __restrict__ out, int N) {
    const int wid  = threadIdx.x >> 6;
    const int lane = threadIdx.x & 63;
    const int ray  = blockIdx.x * WPB + wid;
    __shared__ float cdf_s[WPB][SC];   // wave-private rows; no block barrier needed
    if (ray >= N) return;

    const float L2_10 = 3.3219280948873623f;   // log2(10)
    const float L2_E  = 1.4426950408889634f;   // log2(e)
    const float DLT   = 0.0078125f;            // 1/128
    const float C2  = -4.0f * L2_E;            // exp(-4*ssq)        = 2^(C2*ssq)
    const float C1  = -L2_E * 25.0f * DLT;     // exp(-25*e^..*DLT)  = 2^(C1*sg)
    const float C25 = -L2_E * 25.0f;           // fine: 2^(C25*sg*del)
    const float CADD = 1e-4f / 256.0f;

    float ox = rays_o[ray * 3 + 0], oy = rays_o[ray * 3 + 1], oz = rays_o[ray * 3 + 2];
    float dx = rays_d[ray * 3 + 0], dy = rays_d[ray * 3 + 1], dz = rays_d[ray * 3 + 2];
    {   // normalize direction
        float rn = frsq(dx * dx + dy * dy + dz * dz);
        dx *= rn; dy *= rn; dz *= rn;
    }

    // ---------------- coarse pass: lane owns k = 4*lane .. 4*lane+3 ----------------
    float zl0 = -1.0f + (float)(lane << 2) * DLT;
    float z0  = fexp2(zl0 * L2_10);
    v2f zz[2];
    zz[0].x = z0;                          zz[0].y = z0 * 1.0181517217011025f;  // 10^(1/128)
    zz[1].x = z0 * 1.0366329284377645f;    zz[1].y = z0 * 1.0554494416179205f;  // 10^(2/128),10^(3/128)

    v2f ee[2];
#pragma unroll
    for (int p = 0; p < 2; p++) {
        v2f z  = zz[p];
        v2f px = dx * z + ox, py = dy * z + oy, pz = dz * z + oz;   // pk_fma
        v2f nsq = px * px + py * py + pz * pz;                      // pk
        v2f rn; rn.x = frsq(nsq.x); rn.y = frsq(nsq.y);
        v2f t2 = 2.0f - rn;
        v2f fs = t2 * t2;
        v2f ssq;
        ssq.x = nsq.x > 1.0f ? fs.x : nsq.x;
        ssq.y = nsq.y > 1.0f ? fs.y : nsq.y;
        v2f sr = C2 * ssq;
        v2f sg; sg.x = fexp2(sr.x); sg.y = fexp2(sr.y);             // exp(-4*ssq)
        v2f ea = C1 * sg;
        ee[p].x = fexp2(ea.x); ee[p].y = fexp2(ea.y);               // exp(-sig*DLT)
    }
    if (lane == 63) ee[1].y = 1.0f;        // last delta = 0 -> alpha 0

    // transmittance: exclusive product scan across lanes
    float lp  = (ee[0].x * ee[0].y) * (ee[1].x * ee[1].y);
    float tp  = scan_mul_incl(lp);
    float tin = DPPF(1.0f, tp, WAVE_SHR1, 0xf);

    v2f om0 = 1.0f - ee[0], om1 = 1.0f - ee[1];
    float c1 = ee[0].x, c2 = c1 * ee[0].y, c3 = c2 * ee[1].x;
    v2f t01; t01.x = tin;      t01.y = tin * c1;
    v2f t23; t23.x = tin * c2; t23.y = tin * c3;
    v2f w01 = om0 * t01, w23 = om1 * t23;

    // reweight (scale 0.5 uniform -> cancels in normalization)
    float wprev = DPPF(0.0f, w23.y, WAVE_SHR1, 0xf);    // lane-1's w3; lane0 -> 0
    float wnext = __shfl_down(w01.x, 1, 64);            // lane+1's w0
    if (lane == 63) wnext = 0.0f;
    float m0 = fmaxf(wprev, w01.x), m1 = fmaxf(w01.x, w01.y),
          m2 = fmaxf(w01.y, w23.x), m3 = fmaxf(w23.x, w23.y),
          m4 = fmaxf(w23.y, wnext);
    float wr0 = 0.5f * (m0 + m1) + CADD, wr1 = 0.5f * (m1 + m2) + CADD,
          wr2 = 0.5f * (m2 + m3) + CADD, wr3 = 0.5f * (m3 + m4) + CADD;

    // CDF: lane-local inclusive sums + wave add-scan
    float s0 = wr0, s1 = s0 + wr1, s2 = s1 + wr2, s3 = s2 + wr3;
    float incl = scan_add_incl(s3);
    float exb  = DPPF(0.0f, incl, WAVE_SHR1, 0xf);
    float invT = frcp(readlane63(incl));
    v2f cdfa; cdfa.x = (exb + s0) * invT; cdfa.y = (exb + s1) * invT;
    v2f cdfb; cdfb.x = (exb + s2) * invT; cdfb.y = (exb + s3) * invT;
    *(v2f*)&cdf_s[wid][(lane << 2) + 0] = cdfa;
    *(v2f*)&cdf_s[wid][(lane << 2) + 2] = cdfb;
    const float* cdf = cdf_s[wid];
    // no __syncthreads(): LDS row is wave-private; compiler orders via lgkmcnt

    // ---------------- inverse-CDF sampling: lane owns j = 2*lane, 2*lane+1 ----------------
    float zlf[2];
#pragma unroll
    for (int jj = 0; jj < 2; jj++) {
        int j = (lane << 1) + jj;
        float u = ((float)j + 0.5f) * (1.0f / 128.0f);
        int lo = 0, hi = SC;
#pragma unroll
        for (int it = 0; it < 8; it++) {    // first k with cdf[k] > u
            int mid = (lo + hi) >> 1;
            if (cdf[mid] <= u) lo = mid + 1; else hi = mid;
        }
        int below = lo - 1; if (below < 0) below = 0;
        int above = lo;     if (above > SC - 1) above = SC - 1;
        float c0 = cdf[below], c1v = cdf[above];
        float b0 = -1.0f + (float)below * DLT;
        float b1 = -1.0f + (float)above * DLT;
        float dnm = c1v - c0;
        dnm = (dnm < 1e-8f) ? 1.0f : dnm;
        float t = (u - c0) / dnm;
        t = t < 0.0f ? 0.0f : (t > 1.0f ? 1.0f : t);
        zlf[jj] = fmaf(t, b1 - b0, b0);
    }

    // ---------------- fine render (one packed pair per lane) ----------------
    float zlf2 = __shfl_down(zlf[0], 1, 64);   // zlf[2*lane+2]
    bool  l63  = (lane == 63);
    v2f del; del.x = zlf[1] - zlf[0]; del.y = l63 ? 0.0f : (zlf2 - zlf[1]);
    v2f zf;  zf.x = fexp2(zlf[0] * L2_10); zf.y = fexp2(zlf[1] * L2_10);
    v2f invz; invz.x = frcp(zf.x); invz.y = frcp(zf.y);
    v2f px = dx * zf + ox, py = dy * zf + oy, pz = dz * zf + oz;
    v2f nsq = px * px + py * py + pz * pz;
    v2f rn; rn.x = frsq(nsq.x); rn.y = frsq(nsq.y);
    v2f t2 = 2.0f - rn;
    v2f fs = t2 * t2;
    v2f fc = rn * t2;
    v2f ssq, fac;
    ssq.x = nsq.x > 1.0f ? fs.x : nsq.x;  fac.x = nsq.x > 1.0f ? fc.x : 1.0f;
    ssq.y = nsq.y > 1.0f ? fs.y : nsq.y;  fac.y = nsq.y > 1.0f ? fc.y : 1.0f;
    v2f sr = C2 * ssq;
    v2f sg; sg.x = fexp2(sr.x); sg.y = fexp2(sr.y);        // exp(-4*ssq)
    v2f ea = (C25 * sg) * del;
    v2f ef; ef.x = fexp2(ea.x); ef.y = fexp2(ea.y);        // exp(-sig*del)

    v2f sx = px * fac, sy = py * fac, sz = pz * fac;       // contracted point
    v2f axr = (sx + 0.1f * dx) * (-L2_E);
    v2f axg = (sy + 0.1f * dy) * (-L2_E);
    v2f axb = (sz + 0.1f * dz) * (-L2_E);
    v2f er; er.x = fexp2(axr.x); er.y = fexp2(axr.y);
    v2f eg; eg.x = fexp2(axg.x); eg.y = fexp2(axg.y);
    v2f eb; eb.x = fexp2(axb.x); eb.y = fexp2(axb.y);
    v2f dr = 1.0f + er, dg = 1.0f + eg, db = 1.0f + eb;
    v2f rv; rv.x = frcp(dr.x); rv.y = frcp(dr.y);
    v2f gv; gv.x = frcp(dg.x); gv.y = frcp(dg.y);
    v2f bv; bv.x = frcp(db.x); bv.y = frcp(db.y);

    float lpf  = ef.x * ef.y;
    float tpf  = scan_mul_incl(lpf);
    float tinf = DPPF(1.0f, tpf, WAVE_SHR1, 0xf);
    float wf0 = (1.0f - ef.x) * tinf;
    float wf1 = (1.0f - ef.y) * (tinf * ef.x);
    v2f wfv; wfv.x = wf0; wfv.y = wf1;

    v2f pr = wfv * rv, pg = wfv * gv, pb = wfv * bv, pi = wfv * invz;
    float ar = scan_add_incl(pr.x + pr.y);    // lane63 = total
    float ag = scan_add_incl(pg.x + pg.y);
    float ab = scan_add_incl(pb.x + pb.y);
    float aw = scan_add_incl(wf0 + wf1);
    float ai = scan_add_incl(pi.x + pi.y);

    // ---------------- outputs: [image N*3][wf N*128][zvs N*128][invdepth N] ----------------
    const size_t NN = (size_t)N;
    float* wf_base  = out + 3 * NN;
    float* zvs_base = wf_base + NN * (size_t)SF;
    float* inv_base = zvs_base + NN * (size_t)SF;
    size_t col = (size_t)ray * SF + (size_t)(lane << 1);
    *(float2*)(wf_base + col) = make_float2(wf0, wf1);
    v2f zvs; zvs.x = (zlf[0] + 1.0f) * 0.5f; zvs.y = (zlf[1] + 1.0f) * 0.5f;
    *(float2*)(zvs_base + col) = make_float2(zvs.x, zvs.y);
    if (l63) {
        float om = 1.0f - aw;
        out[ray * 3 + 0] = fmaf(om, bgp[0], ar);
        out[ray * 3 + 1] = fmaf(om, bgp[1], ag);
        out[ray * 3 + 2] = fmaf(om, bgp[2], ab);
        inv_base[ray] = ai;
    }
}

extern "C" void kernel_launch(void* const* d_in, const int* in_sizes, int n_in,
                              void* d_out, int out_size, void* d_ws, size_t ws_size,
                              hipStream_t stream) {
    const float* rays_o = (const float*)d_in[0];
    const float* rays_d = (const float*)d_in[1];
    const float* bg     = (const float*)d_in[2];
    float* out = (float*)d_out;
    int N = in_sizes[0] / 3;
    int blocks = (N + WPB - 1) / WPB;
    nerf_render<<<blocks, BLOCK, 0, stream>>>(rays_o, rays_d, bg, out, N);
}

// Round 4
// 120.537 us; speedup vs baseline: 1.0711x; 1.0192x over previous
//
#include <hip/hip_runtime.h>

#define WPB 4                // waves (rays) per block
#define BLOCK (64 * WPB)
#define SC 256               // coarse samples per ray
#define SF 128               // fine (importance) samples per ray

typedef float v2f __attribute__((ext_vector_type(2)));
typedef float v4f __attribute__((ext_vector_type(4)));

__device__ __forceinline__ float fexp2(float x) {
#if __has_builtin(__builtin_amdgcn_exp2f)
    return __builtin_amdgcn_exp2f(x);
#else
    return exp2f(x);
#endif
}
__device__ __forceinline__ float frcp(float x) {
#if __has_builtin(__builtin_amdgcn_rcpf)
    return __builtin_amdgcn_rcpf(x);
#else
    return 1.0f / x;
#endif
}
__device__ __forceinline__ float frsq(float x) {
#if __has_builtin(__builtin_amdgcn_rsqf)
    return __builtin_amdgcn_rsqf(x);
#else
    return rsqrtf(x);
#endif
}

// DPP move with identity fill: invalid-source lanes AND row_mask-disabled
// lanes read `oldv` (bound_ctrl=false). rmask selects which 16-lane rows
// are written — REQUIRED for the bcast steps of a wave64 scan.
#define DPPF(oldv, x, ctrl, rmask)                                              \
    __int_as_float(__builtin_amdgcn_update_dpp(                                 \
        __float_as_int(oldv), __float_as_int(x), (ctrl), (rmask), 0xf, false))

// gfx9 DPP ctrl codes
#define ROW_SHR1   0x111
#define ROW_SHR2   0x112
#define ROW_SHR4   0x114
#define ROW_SHR8   0x118
#define WAVE_SHL1  0x130   // lane i <- lane i+1 (lane63 -> old)
#define WAVE_SHR1  0x138   // lane i <- lane i-1 (lane0  -> old)
#define ROW_BC15   0x142
#define ROW_BC31   0x143

__device__ __forceinline__ float scan_mul_incl(float x) {
    x *= DPPF(1.0f, x, ROW_SHR1, 0xf);
    x *= DPPF(1.0f, x, ROW_SHR2, 0xf);
    x *= DPPF(1.0f, x, ROW_SHR4, 0xf);
    x *= DPPF(1.0f, x, ROW_SHR8, 0xf);
    x *= DPPF(1.0f, x, ROW_BC15, 0xa);   // rows 1,3 only
    x *= DPPF(1.0f, x, ROW_BC31, 0xc);   // rows 2,3 only
    return x;                      // inclusive product; lane63 = total
}
__device__ __forceinline__ float scan_add_incl(float x) {
    x += DPPF(0.0f, x, ROW_SHR1, 0xf);
    x += DPPF(0.0f, x, ROW_SHR2, 0xf);
    x += DPPF(0.0f, x, ROW_SHR4, 0xf);
    x += DPPF(0.0f, x, ROW_SHR8, 0xf);
    x += DPPF(0.0f, x, ROW_BC15, 0xa);   // rows 1,3 only
    x += DPPF(0.0f, x, ROW_BC31, 0xc);   // rows 2,3 only
    return x;                      // inclusive sum; lane63 = total
}
__device__ __forceinline__ float readlane63(float x) {
    return __int_as_float(__builtin_amdgcn_readlane(__float_as_int(x), 63));
}

__global__ __launch_bounds__(BLOCK) void nerf_render(
    const float* __restrict__ rays_o, const float* __restrict__ rays_d,
    const float* __restrict__ bgp, float* __restrict__ out, int N) {
    const int wid  = threadIdx.x >> 6;
    const int lane = threadIdx.x & 63;
    const int ray  = blockIdx.x * WPB + wid;
    __shared__ float cdf_s[WPB][SC];   // wave-private rows; no block barrier needed
    if (ray >= N) return;

    const float L2_10 = 3.3219280948873623f;   // log2(10)
    const float L2_E  = 1.4426950408889634f;   // log2(e)
    const float DLT   = 0.0078125f;            // 1/128
    const float C2  = -4.0f * L2_E;            // exp(-4*ssq)        = 2^(C2*ssq)
    const float C1  = -L2_E * 25.0f * DLT;     // exp(-25*e^..*DLT)  = 2^(C1*sg)
    const float C25 = -L2_E * 25.0f;           // fine: 2^(C25*sg*del)
    const float CADD = 1e-4f / 256.0f;

    float ox = rays_o[ray * 3 + 0], oy = rays_o[ray * 3 + 1], oz = rays_o[ray * 3 + 2];
    float dx = rays_d[ray * 3 + 0], dy = rays_d[ray * 3 + 1], dz = rays_d[ray * 3 + 2];
    {   // normalize direction
        float rn = frsq(dx * dx + dy * dy + dz * dz);
        dx *= rn; dy *= rn; dz *= rn;
    }

    // ---------------- coarse pass: lane owns k = 4*lane .. 4*lane+3 ----------------
    // (this whole section is BIT-FROZEN: CDF bits decide searchsorted boundaries)
    float zl0 = -1.0f + (float)(lane << 2) * DLT;
    float z0  = fexp2(zl0 * L2_10);
    v2f zz[2];
    zz[0].x = z0;                          zz[0].y = z0 * 1.0181517217011025f;  // 10^(1/128)
    zz[1].x = z0 * 1.0366329284377645f;    zz[1].y = z0 * 1.0554494416179205f;  // 10^(2/128),10^(3/128)

    v2f ee[2];
#pragma unroll
    for (int p = 0; p < 2; p++) {
        v2f z  = zz[p];
        v2f px = dx * z + ox, py = dy * z + oy, pz = dz * z + oz;   // pk_fma
        v2f nsq = px * px + py * py + pz * pz;                      // pk
        v2f rn; rn.x = frsq(nsq.x); rn.y = frsq(nsq.y);
        v2f t2 = 2.0f - rn;
        v2f fs = t2 * t2;
        v2f ssq;
        ssq.x = nsq.x > 1.0f ? fs.x : nsq.x;
        ssq.y = nsq.y > 1.0f ? fs.y : nsq.y;
        v2f sr = C2 * ssq;
        v2f sg; sg.x = fexp2(sr.x); sg.y = fexp2(sr.y);             // exp(-4*ssq)
        v2f ea = C1 * sg;
        ee[p].x = fexp2(ea.x); ee[p].y = fexp2(ea.y);               // exp(-sig*DLT)
    }
    if (lane == 63) ee[1].y = 1.0f;        // last delta = 0 -> alpha 0

    // transmittance: exclusive product scan across lanes
    float lp  = (ee[0].x * ee[0].y) * (ee[1].x * ee[1].y);
    float tp  = scan_mul_incl(lp);
    float tin = DPPF(1.0f, tp, WAVE_SHR1, 0xf);

    v2f om0 = 1.0f - ee[0], om1 = 1.0f - ee[1];
    float c1 = ee[0].x, c2 = c1 * ee[0].y, c3 = c2 * ee[1].x;
    v2f t01; t01.x = tin;      t01.y = tin * c1;
    v2f t23; t23.x = tin * c2; t23.y = tin * c3;
    v2f w01 = om0 * t01, w23 = om1 * t23;

    // reweight (scale 0.5 uniform -> cancels in normalization)
    float wprev = DPPF(0.0f, w23.y, WAVE_SHR1, 0xf);    // lane-1's w3; lane0 -> 0
    float wnext = DPPF(0.0f, w01.x, WAVE_SHL1, 0xf);    // lane+1's w0; lane63 -> 0 (bit-identical)
    float m0 = fmaxf(wprev, w01.x), m1 = fmaxf(w01.x, w01.y),
          m2 = fmaxf(w01.y, w23.x), m3 = fmaxf(w23.x, w23.y),
          m4 = fmaxf(w23.y, wnext);
    float wr0 = 0.5f * (m0 + m1) + CADD, wr1 = 0.5f * (m1 + m2) + CADD,
          wr2 = 0.5f * (m2 + m3) + CADD, wr3 = 0.5f * (m3 + m4) + CADD;

    // CDF: lane-local inclusive sums + wave add-scan
    float s0 = wr0, s1 = s0 + wr1, s2 = s1 + wr2, s3 = s2 + wr3;
    float incl = scan_add_incl(s3);
    float exb  = DPPF(0.0f, incl, WAVE_SHR1, 0xf);
    float invT = frcp(readlane63(incl));
    v2f cdfa; cdfa.x = (exb + s0) * invT; cdfa.y = (exb + s1) * invT;
    v2f cdfb; cdfb.x = (exb + s2) * invT; cdfb.y = (exb + s3) * invT;
    *(v2f*)&cdf_s[wid][(lane << 2) + 0] = cdfa;
    *(v2f*)&cdf_s[wid][(lane << 2) + 2] = cdfb;
    const float* cdf = cdf_s[wid];
    // no __syncthreads(): LDS row is wave-private; compiler orders via lgkmcnt

    // -------- inverse-CDF sampling, 4-ary: 4 dependent LDS levels (was 9) --------
    // Invariant at each level: answer inds in [base, base+S) and cdf[base+S-1] > u
    // (top: cdf[255] ~ 1.0 > u_max = 0.99609). cprev tracks cdf[base-1] when base>0.
    // Selected bin is bit-identical to an 8-step binary searchsorted(side='right').
    float zlf[2];
#pragma unroll
    for (int jj = 0; jj < 2; jj++) {
        int j = (lane << 1) + jj;
        float u = ((float)j + 0.5f) * (1.0f / 128.0f);
        int base = 0;
        float cprev = 0.0f;
#pragma unroll
        for (int S4 = 64; S4 >= 4; S4 >>= 2) {      // levels: 64, 16, 4
            const float* cb = cdf + base;
            float pa = cb[S4 - 1], pb = cb[2 * S4 - 1], pc = cb[3 * S4 - 1];
            int q = (pa <= u) + (pb <= u) + (pc <= u);
            cprev = (pc <= u) ? pc : ((pb <= u) ? pb : ((pa <= u) ? pa : cprev));
            base += q * S4;
        }
        v4f r = *(const v4f*)(cdf + base);          // ds_read_b128, 16B-aligned
        bool le0 = (r.x <= u), le1 = (r.y <= u), le2 = (r.z <= u);  // r.w > u by invariant
        int cnt  = (int)le0 + (int)le1 + (int)le2;
        int inds = base + cnt;
        float c1v = le2 ? r.w : (le1 ? r.z : (le0 ? r.y : r.x));      // cdf[inds]
        float cfb = (base > 0) ? cprev : r.x;                         // cdf[base-1] (or cdf[0])
        float c0  = le2 ? r.z : (le1 ? r.y : (le0 ? r.x : cfb));      // cdf[max(inds-1,0)]
        int below = (inds > 0) ? inds - 1 : 0;
        float b0 = -1.0f + (float)below * DLT;      // exact: small-int * 2^-7
        float b1 = -1.0f + (float)inds * DLT;
        float dnm = c1v - c0;
        dnm = (dnm < 1e-8f) ? 1.0f : dnm;
        float t = (u - c0) * frcp(dnm);
        t = t < 0.0f ? 0.0f : (t > 1.0f ? 1.0f : t);
        zlf[jj] = fmaf(t, b1 - b0, b0);
    }

    // ---------------- fine render (one packed pair per lane) ----------------
    float zlf2 = DPPF(zlf[1], zlf[0], WAVE_SHL1, 0xf);  // zlf[2*lane+2]; lane63 -> own zlf[1] => del.y = 0
    bool  l63  = (lane == 63);
    v2f del; del.x = zlf[1] - zlf[0]; del.y = zlf2 - zlf[1];
    v2f zf;  zf.x = fexp2(zlf[0] * L2_10); zf.y = fexp2(zlf[1] * L2_10);
    v2f invz; invz.x = frcp(zf.x); invz.y = frcp(zf.y);
    v2f px = dx * zf + ox, py = dy * zf + oy, pz = dz * zf + oz;
    v2f nsq = px * px + py * py + pz * pz;
    v2f rn; rn.x = frsq(nsq.x); rn.y = frsq(nsq.y);
    v2f t2 = 2.0f - rn;
    v2f fs = t2 * t2;
    v2f fc = rn * t2;
    v2f ssq, fac;
    ssq.x = nsq.x > 1.0f ? fs.x : nsq.x;  fac.x = nsq.x > 1.0f ? fc.x : 1.0f;
    ssq.y = nsq.y > 1.0f ? fs.y : nsq.y;  fac.y = nsq.y > 1.0f ? fc.y : 1.0f;
    v2f sr = C2 * ssq;
    v2f sg; sg.x = fexp2(sr.x); sg.y = fexp2(sr.y);        // exp(-4*ssq)
    v2f ea = (C25 * sg) * del;
    v2f ef; ef.x = fexp2(ea.x); ef.y = fexp2(ea.y);        // exp(-sig*del)

    v2f sx = px * fac, sy = py * fac, sz = pz * fac;       // contracted point
    v2f axr = (sx + 0.1f * dx) * (-L2_E);
    v2f axg = (sy + 0.1f * dy) * (-L2_E);
    v2f axb = (sz + 0.1f * dz) * (-L2_E);
    v2f er; er.x = fexp2(axr.x); er.y = fexp2(axr.y);
    v2f eg; eg.x = fexp2(axg.x); eg.y = fexp2(axg.y);
    v2f eb; eb.x = fexp2(axb.x); eb.y = fexp2(axb.y);
    v2f dr = 1.0f + er, dg = 1.0f + eg, db = 1.0f + eb;
    v2f rv; rv.x = frcp(dr.x); rv.y = frcp(dr.y);
    v2f gv; gv.x = frcp(dg.x); gv.y = frcp(dg.y);
    v2f bv; bv.x = frcp(db.x); bv.y = frcp(db.y);

    float lpf  = ef.x * ef.y;
    float tpf  = scan_mul_incl(lpf);
    float tinf = DPPF(1.0f, tpf, WAVE_SHR1, 0xf);
    float wf0 = (1.0f - ef.x) * tinf;
    float wf1 = (1.0f - ef.y) * (tinf * ef.x);
    v2f wfv; wfv.x = wf0; wfv.y = wf1;

    v2f pr = wfv * rv, pg = wfv * gv, pb = wfv * bv, pi = wfv * invz;
    float ar = scan_add_incl(pr.x + pr.y);    // lane63 = total
    float ag = scan_add_incl(pg.x + pg.y);
    float ab = scan_add_incl(pb.x + pb.y);
    float aw = scan_add_incl(wf0 + wf1);
    float ai = scan_add_incl(pi.x + pi.y);

    // ---------------- outputs: [image N*3][wf N*128][zvs N*128][invdepth N] ----------------
    const size_t NN = (size_t)N;
    float* wf_base  = out + 3 * NN;
    float* zvs_base = wf_base + NN * (size_t)SF;
    float* inv_base = zvs_base + NN * (size_t)SF;
    size_t col = (size_t)ray * SF + (size_t)(lane << 1);
    *(float2*)(wf_base + col) = make_float2(wf0, wf1);
    v2f zvs; zvs.x = (zlf[0] + 1.0f) * 0.5f; zvs.y = (zlf[1] + 1.0f) * 0.5f;
    *(float2*)(zvs_base + col) = make_float2(zvs.x, zvs.y);
    if (l63) {
        float om = 1.0f - aw;
        out[ray * 3 + 0] = fmaf(om, bgp[0], ar);
        out[ray * 3 + 1] = fmaf(om, bgp[1], ag);
        out[ray * 3 + 2] = fmaf(om, bgp[2], ab);
        inv_base[ray] = ai;
    }
}

extern "C" void kernel_launch(void* const* d_in, const int* in_sizes, int n_in,
                              void* d_out, int out_size, void* d_ws, size_t ws_size,
                              hipStream_t stream) {
    const float* rays_o = (const float*)d_in[0];
    const float* rays_d = (const float*)d_in[1];
    const float* bg     = (const float*)d_in[2];
    float* out = (float*)d_out;
    int N = in_sizes[0] / 3;
    int blocks = (N + WPB - 1) / WPB;
    nerf_render<<<blocks, BLOCK, 0, stream>>>(rays_o, rays_d, bg, out, N);
}

// Round 5
// 118.184 us; speedup vs baseline: 1.0924x; 1.0199x over previous
//
#include <hip/hip_runtime.h>

#define WPB 4                // waves (rays) per block
#define BLOCK (64 * WPB)
#define SC 256               // coarse samples per ray
#define SF 128               // fine (importance) samples per ray

typedef float v2f __attribute__((ext_vector_type(2)));
typedef float v4f __attribute__((ext_vector_type(4)));

__device__ __forceinline__ float fexp2(float x) {
#if __has_builtin(__builtin_amdgcn_exp2f)
    return __builtin_amdgcn_exp2f(x);
#else
    return exp2f(x);
#endif
}
__device__ __forceinline__ float frcp(float x) {
#if __has_builtin(__builtin_amdgcn_rcpf)
    return __builtin_amdgcn_rcpf(x);
#else
    return 1.0f / x;
#endif
}
__device__ __forceinline__ float frsq(float x) {
#if __has_builtin(__builtin_amdgcn_rsqf)
    return __builtin_amdgcn_rsqf(x);
#else
    return rsqrtf(x);
#endif
}

// DPP move. bc=false: invalid/masked lanes read `oldv`.
// bc=true: invalid source lanes read 0 (masked rows still return oldv).
#define DPPF(oldv, x, ctrl, rmask, bc)                                          \
    __int_as_float(__builtin_amdgcn_update_dpp(                                 \
        __float_as_int(oldv), __float_as_int(x), (ctrl), (rmask), 0xf, (bc)))

// gfx9 DPP ctrl codes
#define ROW_SHR1   0x111
#define ROW_SHR2   0x112
#define ROW_SHR4   0x114
#define ROW_SHR8   0x118
#define WAVE_SHL1  0x130   // lane i <- lane i+1 (lane63 -> old)
#define WAVE_SHR1  0x138   // lane i <- lane i-1 (lane0  -> old)
#define ROW_BC15   0x142
#define ROW_BC31   0x143

__device__ __forceinline__ float scan_mul_incl(float x) {
    x *= DPPF(1.0f, x, ROW_SHR1, 0xf, false);
    x *= DPPF(1.0f, x, ROW_SHR2, 0xf, false);
    x *= DPPF(1.0f, x, ROW_SHR4, 0xf, false);
    x *= DPPF(1.0f, x, ROW_SHR8, 0xf, false);
    x *= DPPF(1.0f, x, ROW_BC15, 0xa, false);   // rows 1,3 only
    x *= DPPF(1.0f, x, ROW_BC31, 0xc, false);   // rows 2,3 only
    return x;                      // inclusive product; lane63 = total
}
// bound_ctrl=true: invalid lanes contribute 0 (add identity); masked rows get
// old=0 so x+0=x. Bit-identical values to the bc=false/old=0 form, but the
// compiler can fuse mov_dpp+add into v_add_f32_dpp.
__device__ __forceinline__ float scan_add_incl(float x) {
    x += DPPF(0.0f, x, ROW_SHR1, 0xf, true);
    x += DPPF(0.0f, x, ROW_SHR2, 0xf, true);
    x += DPPF(0.0f, x, ROW_SHR4, 0xf, true);
    x += DPPF(0.0f, x, ROW_SHR8, 0xf, true);
    x += DPPF(0.0f, x, ROW_BC15, 0xa, true);    // rows 1,3 only
    x += DPPF(0.0f, x, ROW_BC31, 0xc, true);    // rows 2,3 only
    return x;                      // inclusive sum; lane63 = total
}
__device__ __forceinline__ float readlanef(float x, int l) {
    return __int_as_float(__builtin_amdgcn_readlane(__float_as_int(x), l));
}

__global__ __launch_bounds__(BLOCK) void nerf_render(
    const float* __restrict__ rays_o, const float* __restrict__ rays_d,
    const float* __restrict__ bgp, float* __restrict__ out, int N) {
    const int wid  = __builtin_amdgcn_readfirstlane(threadIdx.x >> 6);  // wave-uniform -> SGPR
    const int lane = threadIdx.x & 63;
    const int ray  = __builtin_amdgcn_readfirstlane(blockIdx.x * WPB + wid);
    __shared__ float cdf_s[WPB][SC];   // wave-private rows; no block barrier needed

    const float L2_10 = 3.3219280948873623f;   // log2(10)
    const float L2_E  = 1.4426950408889634f;   // log2(e)
    const float DLT   = 0.0078125f;            // 1/128
    const float C2  = -4.0f * L2_E;            // exp(-4*ssq)        = 2^(C2*ssq)
    const float C1  = -L2_E * 25.0f * DLT;     // exp(-25*e^..*DLT)  = 2^(C1*sg)
    const float C25 = -L2_E * 25.0f;           // fine: 2^(C25*sg*del)
    const float CADD = 1e-4f / 256.0f;

    float ox = rays_o[ray * 3 + 0], oy = rays_o[ray * 3 + 1], oz = rays_o[ray * 3 + 2];
    float dx = rays_d[ray * 3 + 0], dy = rays_d[ray * 3 + 1], dz = rays_d[ray * 3 + 2];
    {   // normalize direction
        float rn = frsq(dx * dx + dy * dy + dz * dz);
        dx *= rn; dy *= rn; dz *= rn;
    }

    // ---------------- coarse pass: lane owns k = 4*lane .. 4*lane+3 ----------------
    // (this whole section is BIT-FROZEN: CDF bits decide searchsorted boundaries)
    float zl0 = -1.0f + (float)(lane << 2) * DLT;
    float z0  = fexp2(zl0 * L2_10);
    v2f zz[2];
    zz[0].x = z0;                          zz[0].y = z0 * 1.0181517217011025f;  // 10^(1/128)
    zz[1].x = z0 * 1.0366329284377645f;    zz[1].y = z0 * 1.0554494416179205f;  // 10^(2/128),10^(3/128)

    v2f ee[2];
#pragma unroll
    for (int p = 0; p < 2; p++) {
        v2f z  = zz[p];
        v2f px = dx * z + ox, py = dy * z + oy, pz = dz * z + oz;   // pk_fma
        v2f nsq = px * px + py * py + pz * pz;                      // pk
        v2f rn; rn.x = frsq(nsq.x); rn.y = frsq(nsq.y);
        v2f t2 = 2.0f - rn;
        v2f fs = t2 * t2;
        v2f ssq;
        ssq.x = nsq.x > 1.0f ? fs.x : nsq.x;
        ssq.y = nsq.y > 1.0f ? fs.y : nsq.y;
        v2f sr = C2 * ssq;
        v2f sg; sg.x = fexp2(sr.x); sg.y = fexp2(sr.y);             // exp(-4*ssq)
        v2f ea = C1 * sg;
        ee[p].x = fexp2(ea.x); ee[p].y = fexp2(ea.y);               // exp(-sig*DLT)
    }
    if (lane == 63) ee[1].y = 1.0f;        // last delta = 0 -> alpha 0

    // transmittance: exclusive product scan across lanes
    float lp  = (ee[0].x * ee[0].y) * (ee[1].x * ee[1].y);
    float tp  = scan_mul_incl(lp);
    float tin = DPPF(1.0f, tp, WAVE_SHR1, 0xf, false);

    v2f om0 = 1.0f - ee[0], om1 = 1.0f - ee[1];
    float c1 = ee[0].x, c2 = c1 * ee[0].y, c3 = c2 * ee[1].x;
    v2f t01; t01.x = tin;      t01.y = tin * c1;
    v2f t23; t23.x = tin * c2; t23.y = tin * c3;
    v2f w01 = om0 * t01, w23 = om1 * t23;

    // reweight (scale 0.5 uniform -> cancels in normalization)
    float wprev = DPPF(0.0f, w23.y, WAVE_SHR1, 0xf, false);  // lane-1's w3; lane0 -> 0
    float wnext = DPPF(0.0f, w01.x, WAVE_SHL1, 0xf, false);  // lane+1's w0; lane63 -> 0
    float m0 = fmaxf(wprev, w01.x), m1 = fmaxf(w01.x, w01.y),
          m2 = fmaxf(w01.y, w23.x), m3 = fmaxf(w23.x, w23.y),
          m4 = fmaxf(w23.y, wnext);
    float wr0 = 0.5f * (m0 + m1) + CADD, wr1 = 0.5f * (m1 + m2) + CADD,
          wr2 = 0.5f * (m2 + m3) + CADD, wr3 = 0.5f * (m3 + m4) + CADD;

    // CDF: lane-local inclusive sums + wave add-scan
    float s0 = wr0, s1 = s0 + wr1, s2 = s1 + wr2, s3 = s2 + wr3;
    float incl = scan_add_incl(s3);
    float exb  = DPPF(0.0f, incl, WAVE_SHR1, 0xf, true);
    float invT = frcp(readlanef(incl, 63));
    v2f cdfa; cdfa.x = (exb + s0) * invT; cdfa.y = (exb + s1) * invT;
    v2f cdfb; cdfb.x = (exb + s2) * invT; cdfb.y = (exb + s3) * invT;
    *(v2f*)&cdf_s[wid][(lane << 2) + 0] = cdfa;
    *(v2f*)&cdf_s[wid][(lane << 2) + 2] = cdfb;
    const float* cdf = cdf_s[wid];
    // no __syncthreads(): LDS row is wave-private; compiler orders via lgkmcnt

    // Level-1 pivots are wave-uniform register values: cdf[63]/[127]/[191]
    // live in lanes 15/31/47's cdfb.y. Bit-identical to the LDS copy.
    const float p63  = readlanef(cdfb.y, 15);
    const float p127 = readlanef(cdfb.y, 31);
    const float p191 = readlanef(cdfb.y, 47);

    // -------- inverse-CDF sampling: reg level + 2 LDS levels + final b128 --------
    // Invariant at each level: answer inds in [base, base+S) and cdf[base+S-1] > u
    // (top: cdf[255] ~ 1.0 > u_max = 0.99609). Bin selection bit-identical to
    // np.searchsorted(cdf, u, 'right').
    float zlf[2];
#pragma unroll
    for (int jj = 0; jj < 2; jj++) {
        int j = (lane << 1) + jj;
        float u = ((float)j + 0.5f) * (1.0f / 128.0f);
        int base = (((int)(p63 <= u) + (int)(p127 <= u) + (int)(p191 <= u)) << 6);
        {   // level 2: stride 16
            float qa = cdf[base + 15], qb = cdf[base + 31], qc = cdf[base + 47];
            base += (((int)(qa <= u) + (int)(qb <= u) + (int)(qc <= u)) << 4);
        }
        {   // level 3: stride 4
            float ra_ = cdf[base + 3], rb_ = cdf[base + 7], rc_ = cdf[base + 11];
            base += (((int)(ra_ <= u) + (int)(rb_ <= u) + (int)(rc_ <= u)) << 2);
        }
        v4f r = *(const v4f*)(cdf + base);          // ds_read_b128, 16B-aligned
        int bm1 = base - 1; if (bm1 < 0) bm1 = 0;
        float cm1 = cdf[bm1];                        // cdf[max(base-1,0)] == np's fallback
        bool le0 = (r.x <= u), le1 = (r.y <= u), le2 = (r.z <= u);  // r.w > u by invariant
        int cnt  = (int)le0 + (int)le1 + (int)le2;
        int inds = base + cnt;
        float c1v = le2 ? r.w : (le1 ? r.z : (le0 ? r.y : r.x));    // cdf[inds]
        float c0  = le2 ? r.z : (le1 ? r.y : (le0 ? r.x : cm1));    // cdf[max(inds-1,0)]
        float dnm = c1v - c0;
        dnm = (dnm < 1e-8f) ? 1.0f : dnm;
        float t = (u - c0) * frcp(dnm);
        t = t < 0.0f ? 0.0f : (t > 1.0f ? 1.0f : t);
        // inds>=1: b0=-1+(inds-1)*DLT, b1-b0=DLT exactly; inds==0: zlf=-1
        float f = (inds == 0) ? 0.0f : ((float)(inds - 1) + t);
        zlf[jj] = fmaf(DLT, f, -1.0f);
    }

    // ---------------- fine render (one packed pair per lane) ----------------
    float zlf2 = DPPF(zlf[1], zlf[0], WAVE_SHL1, 0xf, false);  // zlf[2*lane+2]; lane63 -> own zlf[1] => del.y = 0
    bool  l63  = (lane == 63);
    v2f del; del.x = zlf[1] - zlf[0]; del.y = zlf2 - zlf[1];
    v2f zf;  zf.x = fexp2(zlf[0] * L2_10); zf.y = fexp2(zlf[1] * L2_10);
    v2f invz; invz.x = frcp(zf.x); invz.y = frcp(zf.y);
    v2f px = dx * zf + ox, py = dy * zf + oy, pz = dz * zf + oz;
    v2f nsq = px * px + py * py + pz * pz;
    v2f rn; rn.x = frsq(nsq.x); rn.y = frsq(nsq.y);
    v2f t2 = 2.0f - rn;
    v2f fs = t2 * t2;
    v2f fc = rn * t2;
    v2f ssq, fac;
    ssq.x = nsq.x > 1.0f ? fs.x : nsq.x;  fac.x = nsq.x > 1.0f ? fc.x : 1.0f;
    ssq.y = nsq.y > 1.0f ? fs.y : nsq.y;  fac.y = nsq.y > 1.0f ? fc.y : 1.0f;
    v2f sr = C2 * ssq;
    v2f sg; sg.x = fexp2(sr.x); sg.y = fexp2(sr.y);        // exp(-4*ssq)
    v2f ea = (C25 * sg) * del;
    v2f ef; ef.x = fexp2(ea.x); ef.y = fexp2(ea.y);        // exp(-sig*del)

    v2f sx = px * fac, sy = py * fac, sz = pz * fac;       // contracted point
    v2f axr = (sx + 0.1f * dx) * (-L2_E);
    v2f axg = (sy + 0.1f * dy) * (-L2_E);
    v2f axb = (sz + 0.1f * dz) * (-L2_E);
    v2f er; er.x = fexp2(axr.x); er.y = fexp2(axr.y);
    v2f eg; eg.x = fexp2(axg.x); eg.y = fexp2(axg.y);
    v2f eb; eb.x = fexp2(axb.x); eb.y = fexp2(axb.y);
    v2f dr = 1.0f + er, dg = 1.0f + eg, db = 1.0f + eb;
    v2f rv; rv.x = frcp(dr.x); rv.y = frcp(dr.y);
    v2f gv; gv.x = frcp(dg.x); gv.y = frcp(dg.y);
    v2f bv; bv.x = frcp(db.x); bv.y = frcp(db.y);

    float lpf  = ef.x * ef.y;
    float tpf  = scan_mul_incl(lpf);
    float tinf = DPPF(1.0f, tpf, WAVE_SHR1, 0xf, false);
    float wf0 = (1.0f - ef.x) * tinf;
    float wf1 = (1.0f - ef.y) * (tinf * ef.x);
    v2f wfv; wfv.x = wf0; wfv.y = wf1;

    v2f pr = wfv * rv, pg = wfv * gv, pb = wfv * bv, pi = wfv * invz;
    float ar = scan_add_incl(pr.x + pr.y);    // lane63 = total
    float ag = scan_add_incl(pg.x + pg.y);
    float ab = scan_add_incl(pb.x + pb.y);
    float aw = scan_add_incl(wf0 + wf1);
    float ai = scan_add_incl(pi.x + pi.y);

    // ---------------- outputs: [image N*3][wf N*128][zvs N*128][invdepth N] ----------------
    // 32-bit offsets: total elements 65536*260 < 2^25
    const unsigned NN = (unsigned)N;
    float* wf_base  = out + 3u * NN;
    float* zvs_base = wf_base + NN * (unsigned)SF;
    float* inv_base = zvs_base + NN * (unsigned)SF;
    unsigned col = (unsigned)ray * (unsigned)SF + (unsigned)(lane << 1);
    *(float2*)(wf_base + col) = make_float2(wf0, wf1);
    *(float2*)(zvs_base + col) = make_float2((zlf[0] + 1.0f) * 0.5f, (zlf[1] + 1.0f) * 0.5f);
    if (l63) {
        float om = 1.0f - aw;
        out[(unsigned)ray * 3u + 0u] = fmaf(om, bgp[0], ar);
        out[(unsigned)ray * 3u + 1u] = fmaf(om, bgp[1], ag);
        out[(unsigned)ray * 3u + 2u] = fmaf(om, bgp[2], ab);
        inv_base[(unsigned)ray] = ai;
    }
}

extern "C" void kernel_launch(void* const* d_in, const int* in_sizes, int n_in,
                              void* d_out, int out_size, void* d_ws, size_t ws_size,
                              hipStream_t stream) {
    const float* rays_o = (const float*)d_in[0];
    const float* rays_d = (const float*)d_in[1];
    const float* bg     = (const float*)d_in[2];
    float* out = (float*)d_out;
    int N = in_sizes[0] / 3;
    int blocks = (N + WPB - 1) / WPB;
    nerf_render<<<blocks, BLOCK, 0, stream>>>(rays_o, rays_d, bg, out, N);
}

// Round 6
// 116.611 us; speedup vs baseline: 1.1072x; 1.0135x over previous
//
#include <hip/hip_runtime.h>

#define WPB 4                // waves (rays) per block
#define BLOCK (64 * WPB)
#define SC 256               // coarse samples per ray
#define SF 128               // fine (importance) samples per ray

typedef float v2f __attribute__((ext_vector_type(2)));
typedef float v4f __attribute__((ext_vector_type(4)));

__device__ __forceinline__ float fexp2(float x) {
#if __has_builtin(__builtin_amdgcn_exp2f)
    return __builtin_amdgcn_exp2f(x);
#else
    return exp2f(x);
#endif
}
__device__ __forceinline__ float frcp(float x) {
#if __has_builtin(__builtin_amdgcn_rcpf)
    return __builtin_amdgcn_rcpf(x);
#else
    return 1.0f / x;
#endif
}
__device__ __forceinline__ float frsq(float x) {
#if __has_builtin(__builtin_amdgcn_rsqf)
    return __builtin_amdgcn_rsqf(x);
#else
    return rsqrtf(x);
#endif
}

// DPP move. bc=false: invalid/masked lanes read `oldv`.
// bc=true: invalid source lanes read 0 (masked rows still return oldv).
#define DPPF(oldv, x, ctrl, rmask, bc)                                          \
    __int_as_float(__builtin_amdgcn_update_dpp(                                 \
        __float_as_int(oldv), __float_as_int(x), (ctrl), (rmask), 0xf, (bc)))

// gfx9 DPP ctrl codes
#define ROW_SHR1   0x111
#define ROW_SHR2   0x112
#define ROW_SHR4   0x114
#define ROW_SHR8   0x118
#define WAVE_SHL1  0x130   // lane i <- lane i+1 (lane63 -> old)
#define WAVE_SHR1  0x138   // lane i <- lane i-1 (lane0  -> old)
#define ROW_BC15   0x142
#define ROW_BC31   0x143

__device__ __forceinline__ float scan_mul_incl(float x) {
    x *= DPPF(1.0f, x, ROW_SHR1, 0xf, false);
    x *= DPPF(1.0f, x, ROW_SHR2, 0xf, false);
    x *= DPPF(1.0f, x, ROW_SHR4, 0xf, false);
    x *= DPPF(1.0f, x, ROW_SHR8, 0xf, false);
    x *= DPPF(1.0f, x, ROW_BC15, 0xa, false);   // rows 1,3 only
    x *= DPPF(1.0f, x, ROW_BC31, 0xc, false);   // rows 2,3 only
    return x;                      // inclusive product; lane63 = total
}
// bound_ctrl=true: invalid lanes contribute 0 (add identity); masked rows get
// old=0 so x+0=x. Fusable into v_add_f32_dpp.
__device__ __forceinline__ float scan_add_incl(float x) {
    x += DPPF(0.0f, x, ROW_SHR1, 0xf, true);
    x += DPPF(0.0f, x, ROW_SHR2, 0xf, true);
    x += DPPF(0.0f, x, ROW_SHR4, 0xf, true);
    x += DPPF(0.0f, x, ROW_SHR8, 0xf, true);
    x += DPPF(0.0f, x, ROW_BC15, 0xa, true);    // rows 1,3 only
    x += DPPF(0.0f, x, ROW_BC31, 0xc, true);    // rows 2,3 only
    return x;                      // inclusive sum; lane63 = total
}
__device__ __forceinline__ float readlanef(float x, int l) {
    return __int_as_float(__builtin_amdgcn_readlane(__float_as_int(x), l));
}

__global__ __launch_bounds__(BLOCK) void nerf_render(
    const float* __restrict__ rays_o, const float* __restrict__ rays_d,
    const float* __restrict__ bgp, float* __restrict__ out, int N) {
    const int wid  = __builtin_amdgcn_readfirstlane(threadIdx.x >> 6);  // wave-uniform -> SGPR
    const int lane = threadIdx.x & 63;
    const int ray  = __builtin_amdgcn_readfirstlane(blockIdx.x * WPB + wid);
    __shared__ float cdf_s[WPB][SC];   // wave-private rows; no block barrier needed

    const float L2_10 = 3.3219280948873623f;   // log2(10)
    const float L2_E  = 1.4426950408889634f;   // log2(e)
    const float DLT   = 0.0078125f;            // 1/128
    const float C2  = -4.0f * L2_E;            // exp(-4*ssq)        = 2^(C2*ssq)
    const float C1  = -L2_E * 25.0f * DLT;     // exp(-25*e^..*DLT)  = 2^(C1*sg)
    const float C25 = -L2_E * 25.0f;           // fine: 2^(C25*sg*del)
    const float CADD = 1e-4f / 256.0f;

    float ox = rays_o[ray * 3 + 0], oy = rays_o[ray * 3 + 1], oz = rays_o[ray * 3 + 2];
    float dx = rays_d[ray * 3 + 0], dy = rays_d[ray * 3 + 1], dz = rays_d[ray * 3 + 2];
    {   // normalize direction
        float rn = frsq(dx * dx + dy * dy + dz * dz);
        dx *= rn; dy *= rn; dz *= rn;
    }
    // sigmoid direction-bias, pre-scaled for a single pk_fma per channel
    float dxn = dx * (-0.1f * L2_E), dyn = dy * (-0.1f * L2_E), dzn = dz * (-0.1f * L2_E);

    // ---------------- coarse pass: lane owns k = 4*lane .. 4*lane+3 ----------------
    // (this whole section is BIT-FROZEN: CDF bits decide searchsorted boundaries)
    float zl0 = -1.0f + (float)(lane << 2) * DLT;
    float z0  = fexp2(zl0 * L2_10);
    v2f zz[2];
    zz[0].x = z0;                          zz[0].y = z0 * 1.0181517217011025f;  // 10^(1/128)
    zz[1].x = z0 * 1.0366329284377645f;    zz[1].y = z0 * 1.0554494416179205f;  // 10^(2/128),10^(3/128)

    v2f ee[2];
#pragma unroll
    for (int p = 0; p < 2; p++) {
        v2f z  = zz[p];
        v2f px = dx * z + ox, py = dy * z + oy, pz = dz * z + oz;   // pk_fma
        v2f nsq = px * px + py * py + pz * pz;                      // pk
        v2f rn; rn.x = frsq(nsq.x); rn.y = frsq(nsq.y);
        v2f t2 = 2.0f - rn;
        v2f fs = t2 * t2;
        v2f ssq;
        ssq.x = nsq.x > 1.0f ? fs.x : nsq.x;
        ssq.y = nsq.y > 1.0f ? fs.y : nsq.y;
        v2f sr = C2 * ssq;
        v2f sg; sg.x = fexp2(sr.x); sg.y = fexp2(sr.y);             // exp(-4*ssq)
        v2f ea = C1 * sg;
        ee[p].x = fexp2(ea.x); ee[p].y = fexp2(ea.y);               // exp(-sig*DLT)
    }
    if (lane == 63) ee[1].y = 1.0f;        // last delta = 0 -> alpha 0

    // transmittance: exclusive product scan across lanes
    float lp  = (ee[0].x * ee[0].y) * (ee[1].x * ee[1].y);
    float tp  = scan_mul_incl(lp);
    float tin = DPPF(1.0f, tp, WAVE_SHR1, 0xf, false);

    v2f om0 = 1.0f - ee[0], om1 = 1.0f - ee[1];
    float c1 = ee[0].x, c2 = c1 * ee[0].y, c3 = c2 * ee[1].x;
    v2f t01; t01.x = tin;      t01.y = tin * c1;
    v2f t23; t23.x = tin * c2; t23.y = tin * c3;
    v2f w01 = om0 * t01, w23 = om1 * t23;

    // reweight (scale 0.5 uniform -> cancels in normalization)
    float wprev = DPPF(0.0f, w23.y, WAVE_SHR1, 0xf, false);  // lane-1's w3; lane0 -> 0
    float wnext = DPPF(0.0f, w01.x, WAVE_SHL1, 0xf, false);  // lane+1's w0; lane63 -> 0
    float m0 = fmaxf(wprev, w01.x), m1 = fmaxf(w01.x, w01.y),
          m2 = fmaxf(w01.y, w23.x), m3 = fmaxf(w23.x, w23.y),
          m4 = fmaxf(w23.y, wnext);
    float wr0 = 0.5f * (m0 + m1) + CADD, wr1 = 0.5f * (m1 + m2) + CADD,
          wr2 = 0.5f * (m2 + m3) + CADD, wr3 = 0.5f * (m3 + m4) + CADD;

    // CDF: lane-local inclusive sums + wave add-scan
    float s0 = wr0, s1 = s0 + wr1, s2 = s1 + wr2, s3 = s2 + wr3;
    float incl = scan_add_incl(s3);
    float exb  = DPPF(0.0f, incl, WAVE_SHR1, 0xf, true);
    float invT = frcp(readlanef(incl, 63));
    v2f cdfa; cdfa.x = (exb + s0) * invT; cdfa.y = (exb + s1) * invT;
    v2f cdfb; cdfb.x = (exb + s2) * invT; cdfb.y = (exb + s3) * invT;
    *(v2f*)&cdf_s[wid][(lane << 2) + 0] = cdfa;
    *(v2f*)&cdf_s[wid][(lane << 2) + 2] = cdfb;
    const float* cdf = cdf_s[wid];
    // no __syncthreads(): LDS row is wave-private; compiler orders via lgkmcnt

    // Level-1 pivots are wave-uniform register values: cdf[63]/[127]/[191]
    // live in lanes 15/31/47's cdfb.y. Bit-identical to the LDS copy.
    const float p63  = readlanef(cdfb.y, 15);
    const float p127 = readlanef(cdfb.y, 31);
    const float p191 = readlanef(cdfb.y, 47);

    // -------- inverse-CDF sampling: reg level + 2 LDS levels + final b128 --------
    // Invariant at each level: answer inds in [base, base+S) and cdf[base+S-1] > u
    // (top: cdf[255] ~ 1.0 > u_max = 0.99609). Bin selection bit-identical to
    // np.searchsorted(cdf, u, 'right').
    float zlf[2];
#pragma unroll
    for (int jj = 0; jj < 2; jj++) {
        int j = (lane << 1) + jj;
        float u = ((float)j + 0.5f) * (1.0f / 128.0f);
        int base = (((int)(p63 <= u) + (int)(p127 <= u) + (int)(p191 <= u)) << 6);
        {   // level 2: stride 16
            float qa = cdf[base + 15], qb = cdf[base + 31], qc = cdf[base + 47];
            base += (((int)(qa <= u) + (int)(qb <= u) + (int)(qc <= u)) << 4);
        }
        {   // level 3: stride 4
            float ra_ = cdf[base + 3], rb_ = cdf[base + 7], rc_ = cdf[base + 11];
            base += (((int)(ra_ <= u) + (int)(rb_ <= u) + (int)(rc_ <= u)) << 2);
        }
        v4f r = *(const v4f*)(cdf + base);          // ds_read_b128, 16B-aligned
        int bm1 = base - 1; if (bm1 < 0) bm1 = 0;
        float cm1 = cdf[bm1];                        // cdf[max(base-1,0)] == np's fallback
        bool le0 = (r.x <= u), le1 = (r.y <= u), le2 = (r.z <= u);  // r.w > u by invariant
        int cnt  = (int)le0 + (int)le1 + (int)le2;
        int inds = base + cnt;
        float c1v = le2 ? r.w : (le1 ? r.z : (le0 ? r.y : r.x));    // cdf[inds]
        float c0  = le2 ? r.z : (le1 ? r.y : (le0 ? r.x : cm1));    // cdf[max(inds-1,0)]
        float dnm = c1v - c0;
        dnm = (dnm < 1e-8f) ? 1.0f : dnm;
        float t = (u - c0) * frcp(dnm);
        t = t < 0.0f ? 0.0f : (t > 1.0f ? 1.0f : t);
        // inds>=1: b0=-1+(inds-1)*DLT, b1-b0=DLT exactly; inds==0: zlf=-1
        float f = (inds == 0) ? 0.0f : ((float)(inds - 1) + t);
        zlf[jj] = fmaf(DLT, f, -1.0f);
    }

    // ---------------- fine render (one packed pair per lane) ----------------
    float zlf2 = DPPF(zlf[1], zlf[0], WAVE_SHL1, 0xf, false);  // zlf[2*lane+2]; lane63 -> own zlf[1] => del.y = 0
    v2f del; del.x = zlf[1] - zlf[0]; del.y = zlf2 - zlf[1];
    v2f zf;  zf.x = fexp2(zlf[0] * L2_10); zf.y = fexp2(zlf[1] * L2_10);
    v2f invz; invz.x = frcp(zf.x); invz.y = frcp(zf.y);
    v2f px = dx * zf + ox, py = dy * zf + oy, pz = dz * zf + oz;
    v2f nsq = px * px + py * py + pz * pz;
    v2f rn; rn.x = frsq(nsq.x); rn.y = frsq(nsq.y);
    v2f t2 = 2.0f - rn;
    v2f fs = t2 * t2;
    v2f fc = rn * t2;
    v2f ssq, fac;
    ssq.x = nsq.x > 1.0f ? fs.x : nsq.x;  fac.x = nsq.x > 1.0f ? fc.x : 1.0f;
    ssq.y = nsq.y > 1.0f ? fs.y : nsq.y;  fac.y = nsq.y > 1.0f ? fc.y : 1.0f;
    v2f sr = C2 * ssq;
    v2f sg; sg.x = fexp2(sr.x); sg.y = fexp2(sr.y);        // exp(-4*ssq)
    v2f ea = (C25 * sg) * del;                             // log2(ef)  (lane63: ea.y = 0 exactly)
    v2f ef; ef.x = fexp2(ea.x); ef.y = fexp2(ea.y);        // exp(-sig*del)

    v2f sx = px * fac, sy = py * fac, sz = pz * fac;       // contracted point
    v2f axr = sx * (-L2_E) + dxn;                          // pk_mul + pk_fma per channel
    v2f axg = sy * (-L2_E) + dyn;
    v2f axb = sz * (-L2_E) + dzn;
    v2f er; er.x = fexp2(axr.x); er.y = fexp2(axr.y);
    v2f eg; eg.x = fexp2(axg.x); eg.y = fexp2(axg.y);
    v2f eb; eb.x = fexp2(axb.x); eb.y = fexp2(axb.y);
    v2f dr = 1.0f + er, dg = 1.0f + eg, db = 1.0f + eb;
    v2f rv; rv.x = frcp(dr.x); rv.y = frcp(dr.y);
    v2f gv; gv.x = frcp(dg.x); gv.y = frcp(dg.y);
    v2f bv; bv.x = frcp(db.x); bv.y = frcp(db.y);

    // log-domain transmittance: fused add-scan on log2(ef) + one exp2
    float asum = ea.x + ea.y;
    float tincl = scan_add_incl(asum);                       // inclusive log-sum
    float texc  = DPPF(0.0f, tincl, WAVE_SHR1, 0xf, true);   // exclusive; lane0 -> 0
    float tinf  = fexp2(texc);                               // incoming transmittance
    float Ttot  = fexp2(readlanef(tincl, 63));               // total transmittance = 1 - sum(wf)
    float wf0 = (1.0f - ef.x) * tinf;
    float wf1 = (1.0f - ef.y) * (tinf * ef.x);
    v2f wfv; wfv.x = wf0; wfv.y = wf1;

    v2f pr = wfv * rv, pg = wfv * gv, pb = wfv * bv, pi = wfv * invz;
    float ar = scan_add_incl(pr.x + pr.y);    // lane63 = total
    float ag = scan_add_incl(pg.x + pg.y);
    float ab = scan_add_incl(pb.x + pb.y);
    float ai = scan_add_incl(pi.x + pi.y);

    // ---------------- outputs: [image N*3][wf N*128][zvs N*128][invdepth N] ----------------
    // 32-bit offsets: total elements 65536*260 < 2^25
    const unsigned NN = (unsigned)N;
    float* wf_base  = out + 3u * NN;
    float* zvs_base = wf_base + NN * (unsigned)SF;
    float* inv_base = zvs_base + NN * (unsigned)SF;
    unsigned col = (unsigned)ray * (unsigned)SF + (unsigned)(lane << 1);
    *(float2*)(wf_base + col) = make_float2(wf0, wf1);
    *(float2*)(zvs_base + col) = make_float2((zlf[0] + 1.0f) * 0.5f, (zlf[1] + 1.0f) * 0.5f);
    if (lane == 63) {
        out[(unsigned)ray * 3u + 0u] = fmaf(Ttot, bgp[0], ar);
        out[(unsigned)ray * 3u + 1u] = fmaf(Ttot, bgp[1], ag);
        out[(unsigned)ray * 3u + 2u] = fmaf(Ttot, bgp[2], ab);
        inv_base[(unsigned)ray] = ai;
    }
}

extern "C" void kernel_launch(void* const* d_in, const int* in_sizes, int n_in,
                              void* d_out, int out_size, void* d_ws, size_t ws_size,
                              hipStream_t stream) {
    const float* rays_o = (const float*)d_in[0];
    const float* rays_d = (const float*)d_in[1];
    const float* bg     = (const float*)d_in[2];
    float* out = (float*)d_out;
    int N = in_sizes[0] / 3;
    int blocks = (N + WPB - 1) / WPB;
    nerf_render<<<blocks, BLOCK, 0, stream>>>(rays_o, rays_d, bg, out, N);
}